// Round 12
// baseline (383.177 us; speedup 1.0000x reference)
//
#include <hip/hip_runtime.h>

#define DECAYF 0.999f
#define GAINF  0.001f
#define EPSF   1e-6f

// Problem sizes (compile-time): B=512, D=64 dim_codes, K=1024 book, E=64 embed
// out layout: cw[512*4096] | one_hot[512*64*1024] | new_cb[64*1024*64] | new_ema[64*1024]
// d_ws deliberately unused.

#define NB 512
#define ND 64
#define NK 1024
#define NE 64

// ---------------- pre-init: ncb = cb*DECAY ; nema = ema*DECAY ----------------
__global__ void k_pre(const float* __restrict__ cb, const float* __restrict__ ema,
                      float* __restrict__ ncb, float* __restrict__ nema) {
    int i = blockIdx.x * blockDim.x + threadIdx.x;   // 1,064,960 float4s total
    if (i < 1048576) {
        float4 v = ((const float4*)cb)[i];
        v.x *= DECAYF; v.y *= DECAYF; v.z *= DECAYF; v.w *= DECAYF;
        ((float4*)ncb)[i] = v;
    } else {
        int j = i - 1048576;
        float4 v = ((const float4*)ema)[j];
        v.x *= DECAYF; v.y *= DECAYF; v.z *= DECAYF; v.w *= DECAYF;
        ((float4*)nema)[j] = v;
    }
}

// ---------------- fused: argmin -> one_hot + cw + scatter + ema ----------------
// ROUND-12 INVERSION. Evidence r10/r11: scan bound by scalar-cache MISS stream
// (each block streams 256KB codebook through K$; 134MB total misses; VALUBusy
// stuck ~30% at both 4 and 8 waves/SIMD -> shared-resource bound, TLP null).
// Fix: swap which operand rides which path.
//   lane = k: wave's 64-code tile loaded ONCE into 64 VGPRs (vector path, 16
//   loads/wave total); x rows (wave-uniform addr) ride the SCALAR path, and the
//   per-block x working set is 16KB -> K$-RESIDENT (misses 134MB -> ~8MB).
//   dist = hb - dot is lane-local; per-b argmin = monotone-u32 map + 6-step
//   shfl_xor min + ballot/ctz (lowest lane = lowest k = ref first-index rule).
// hb (0.5*sum c^2) computed in-register: phase a + s_hbsq LDS eliminated.
// __launch_bounds__(1024,4): VGPR cap 128 >= ~90 live (c_reg 64 + temps).
//   (r8 lesson: never cap below live state; r5: never let allocator clamp to 64.)
// grid (64 d, 8 bq): d%8 XCD affinity (r5: FETCH 143->20MB).
__global__ __launch_bounds__(1024, 4) void k_fused(
        const float* __restrict__ x, const float* __restrict__ cb,
        const float* __restrict__ ema,
        float* __restrict__ cw, float* __restrict__ oh,
        float* __restrict__ ncb, float* __restrict__ nema) {
    const int d    = blockIdx.x;
    const int bq   = blockIdx.y;        // b-chunk 0..7 (64 rows each)
    const int t    = threadIdx.x;
    const int lane = t & 63;            // k within wave tile
    const int w    = __builtin_amdgcn_readfirstlane(t >> 6);  // wave 0..15 = k-16th

    __shared__ unsigned int s_ub[16][64];   // mapped-u32 best per (wave, b)
    __shared__ int          s_ix[16][64];
    __shared__ int          s_kf[64];
    __shared__ int          s_cnt[NK];

    s_cnt[t] = 0;

    // phase b setup: this lane's codebook row (global k = w*64+lane) -> 64 VGPRs
    const float* cbd = cb + (size_t)d * (NK * NE);
    float c_reg[64];
    {
        const float4* crow4 = (const float4*)(cbd + ((size_t)(w * 64) + lane) * NE);
#pragma unroll
        for (int e4 = 0; e4 < 16; ++e4) {
            float4 v = crow4[e4];
            c_reg[e4 * 4 + 0] = v.x; c_reg[e4 * 4 + 1] = v.y;
            c_reg[e4 * 4 + 2] = v.z; c_reg[e4 * 4 + 3] = v.w;
        }
    }
    float h0 = 0.f, h1 = 0.f, h2 = 0.f, h3 = 0.f;
#pragma unroll
    for (int e = 0; e < 64; e += 4) {
        h0 = fmaf(c_reg[e],     c_reg[e],     h0);
        h1 = fmaf(c_reg[e + 1], c_reg[e + 1], h1);
        h2 = fmaf(c_reg[e + 2], c_reg[e + 2], h2);
        h3 = fmaf(c_reg[e + 3], c_reg[e + 3], h3);
    }
    const float hb = 0.5f * ((h0 + h1) + (h2 + h3));

    // phase b: loop over the chunk's 64 b-rows; x row via wave-uniform s_load
    // (16KB/block, K$-resident). argmin(dist) == argmin(hb - dot).
    for (int b = 0; b < 64; ++b) {
        const float* xrow = x + (size_t)(bq * 64 + b) * (ND * NE) + d * NE;  // uniform
        float a0 = 0.f, a1 = 0.f, a2 = 0.f, a3 = 0.f;
#pragma unroll
        for (int e = 0; e < 64; e += 4) {
            a0 = fmaf(xrow[e],     c_reg[e],     a0);   // s_load + v_fma(v,s,v)
            a1 = fmaf(xrow[e + 1], c_reg[e + 1], a1);
            a2 = fmaf(xrow[e + 2], c_reg[e + 2], a2);
            a3 = fmaf(xrow[e + 3], c_reg[e + 3], a3);
        }
        float dist = hb - ((a0 + a1) + (a2 + a3));
        // monotone map fp32 -> u32 (strictly order-preserving, no NaN in data)
        unsigned int u = __float_as_uint(dist);
        u = (u & 0x80000000u) ? ~u : (u | 0x80000000u);
        const unsigned int u0 = u;
#pragma unroll
        for (int m = 1; m < 64; m <<= 1) {
            unsigned int o = (unsigned int)__shfl_xor((int)u, m, 64);
            u = (o < u) ? o : u;
        }
        unsigned long long eq = __ballot(u0 == u);
        if (lane == 0) {
            s_ub[w][b] = u;
            s_ix[w][b] = w * 64 + (int)__builtin_ctzll(eq);  // lowest lane = lowest k
        }
    }
    __syncthreads();

    // phase c: per-b reduce over the 16 ascending k-16ths (strict < keeps earliest)
    if (t < 64) {
        unsigned int bv = s_ub[0][t];
        int bk = s_ix[0][t];
#pragma unroll
        for (int j = 1; j < 16; ++j) {
            unsigned int ob = s_ub[j][t];
            if (ob < bv) { bv = ob; bk = s_ix[j][t]; }
        }
        s_kf[t] = bk;
        atomicAdd(&s_cnt[bk], 1);    // LDS histogram
    }
    __syncthreads();

    // phase d: one-hot rows. Wave w owns rows w*4..w*4+3; 4KB contiguous per row.
    for (int rr = 0; rr < 4; ++rr) {
        int r  = w * 4 + rr;
        int kk = s_kf[r];
        float* orow = oh + (size_t)(bq * 64 + r) * (ND * NK) + d * NK;
#pragma unroll
        for (int j = 0; j < 4; ++j) {
            int k0 = j * 256 + lane * 4;
            float4 o;
            o.x = (k0     == kk) ? 1.f : 0.f;
            o.y = (k0 + 1 == kk) ? 1.f : 0.f;
            o.z = (k0 + 2 == kk) ? 1.f : 0.f;
            o.w = (k0 + 3 == kk) ? 1.f : 0.f;
            *(float4*)(orow + k0) = o;
        }
    }

    // phase e+f: cw rows (exact reference arithmetic x+(c-x)) + scatter into ncb
    for (int rr = 0; rr < 4; ++rr) {
        int r  = w * 4 + rr;
        int kk = s_kf[r];
        int br = bq * 64 + r;
        float xv = x[(size_t)br * (ND * NE) + d * NE + lane];
        float cv = cbd[(size_t)kk * NE + lane];
        cw[(size_t)br * (ND * NE) + d * NE + lane] = xv + (cv - xv);
        float scale = GAINF / (ema[d * NK + kk] + EPSF);
        atomicAdd(&ncb[(size_t)d * (NK * NE) + (size_t)kk * NE + lane], scale * xv);
    }

    // phase g: flush histogram into nema (<= 8 blocks collide per bin)
    {
        int c = s_cnt[t];
        if (c) atomicAdd(&nema[d * NK + t], GAINF * (float)c);
    }
}

extern "C" void kernel_launch(void* const* d_in, const int* in_sizes, int n_in,
                              void* d_out, int out_size, void* d_ws, size_t ws_size,
                              hipStream_t stream) {
    const float* x   = (const float*)d_in[0];   // [512,4096]
    const float* cb  = (const float*)d_in[1];   // [64,1024,64]
    const float* ema = (const float*)d_in[2];   // [64,1024]
    (void)d_ws; (void)ws_size;

    float* out  = (float*)d_out;
    float* cw   = out;                          // 2,097,152
    float* oh   = out + 2097152;                // 33,554,432
    float* ncb  = out + 2097152 + 33554432;     // 4,194,304
    float* nema = ncb + 4194304;                // 65,536

    k_pre<<<4160, 256, 0, stream>>>(cb, ema, ncb, nema);

    dim3 g_fused(64, 8);                        // d on x -> XCD-aligned codebook reuse
    k_fused<<<g_fused, 1024, 0, stream>>>(x, cb, ema, cw, oh, ncb, nema);
}

// Round 13
// 265.543 us; speedup vs baseline: 1.4430x; 1.4430x over previous
//
#include <hip/hip_runtime.h>

#define DECAYF 0.999f
#define GAINF  0.001f
#define EPSF   1e-6f

// Problem sizes (compile-time): B=512, D=64 dim_codes, K=1024 book, E=64 embed
// out layout: cw[512*4096] | one_hot[512*64*1024] | new_cb[64*1024*64] | new_ema[64*1024]
// d_ws deliberately unused.

#define NB 512
#define ND 64
#define NK 1024
#define NE 64

// ---------------- pre-init: ncb = cb*DECAY ; nema = ema*DECAY ----------------
__global__ void k_pre(const float* __restrict__ cb, const float* __restrict__ ema,
                      float* __restrict__ ncb, float* __restrict__ nema) {
    int i = blockIdx.x * blockDim.x + threadIdx.x;   // 1,064,960 float4s total
    if (i < 1048576) {
        float4 v = ((const float4*)cb)[i];
        v.x *= DECAYF; v.y *= DECAYF; v.z *= DECAYF; v.w *= DECAYF;
        ((float4*)ncb)[i] = v;
    } else {
        int j = i - 1048576;
        float4 v = ((const float4*)ema)[j];
        v.x *= DECAYF; v.y *= DECAYF; v.z *= DECAYF; v.w *= DECAYF;
        ((float4*)nema)[j] = v;
    }
}

// ---------------- fused: hbsq -> argmin -> one_hot + cw + scatter + ema ----------------
// ROUND-13: r10/r11 body (scalar-path codebook scan: the 302->122 win), geometry
// changed to cut SCALAR-CACHE MISS VOLUME per CU — the model that fits r10==r11
// (both: 2 blocks/CU x 256KB k-stream = 512KB misses/CU, identical ~90us scan,
// VALUBusy pinned ~30% at 4 AND 8 waves/SIMD -> shared-resource bound).
//   grid (64 d, 4 bq) = 256 blocks = 1 block/CU -> 256KB misses/CU (halved).
//   block = 1024 thr = 16 waves = 2 b-halves x 8 k-eighths; wave pair (2ks+0,
//   2ks+1) reads the SAME 32KB k-stream for different b-rows -> second reader
//   hits K$/L2 instead of adding misses.
// Phase a (hbsq, coalesced vector reads) warms L2 for the scalar stream.
// Plain __launch_bounds__ (r8/r12 lesson: never pin min-waves; allocator wins).
// d on grid-x keeps d%8 XCD affinity (r5: FETCH 143->20MB).
__global__ __launch_bounds__(1024) void k_fused(
        const float* __restrict__ x, const float* __restrict__ cb,
        const float* __restrict__ ema,
        float* __restrict__ cw, float* __restrict__ oh,
        float* __restrict__ ncb, float* __restrict__ nema) {
    const int d    = blockIdx.x;
    const int bq   = blockIdx.y;        // b-chunk 0..3 (128 rows each)
    const int t    = threadIdx.x;
    const int lane = t & 63;            // b within half
    const int wv   = __builtin_amdgcn_readfirstlane(t >> 6);  // wave 0..15
    const int bh   = wv & 1;            // b-half sharing the k-stream
    const int ks   = wv >> 1;           // k-eighth 0..7

    __shared__ float s_hbsq[NK];        // 0.5*sum(c^2): dist' = hbsq - dot
    __shared__ float s_best[8][128];
    __shared__ int   s_idx[8][128];
    __shared__ int   s_kf[128];
    __shared__ int   s_cnt[NK];

    s_cnt[t] = 0;

    // phase a: half-b_sq for this d (one row/thread, coalesced f4 stream; warms L2)
    const float* cbd = cb + (size_t)d * (NK * NE);
    {
        const float4* c4a = (const float4*)(cbd + (size_t)t * NE);
        float a0 = 0.f, a1 = 0.f, a2 = 0.f, a3 = 0.f;
#pragma unroll
        for (int e4 = 0; e4 < 16; ++e4) {
            float4 v = c4a[e4];
            a0 = fmaf(v.x, v.x, a0); a1 = fmaf(v.y, v.y, a1);
            a2 = fmaf(v.z, v.z, a2); a3 = fmaf(v.w, v.w, a3);
        }
        s_hbsq[t] = 0.5f * ((a0 + a1) + (a2 + a3));
    }
    __syncthreads();

    // phase b: wave (bh,ks) scans k in [ks*128, ks*128+128) for its 64 b-rows
    // (lane=b). x row in VGPR/AGPR, loaded once; codebook row via wave-uniform
    // scalar loads (s_load -> SGPRs; no vector-memory traffic in the loop).
    // argmin(dist) == argmin(hbsq - dot)  (x_sq const shift, x2 positive scale)
    const int bl = bh * 64 + lane;      // local row 0..127
    const int b  = bq * 128 + bl;
    float4 xr[16];
    const float4* xp4 = (const float4*)(x + (size_t)b * (ND * NE) + d * NE);
#pragma unroll
    for (int e4 = 0; e4 < 16; ++e4) xr[e4] = xp4[e4];

    const float* crow = cbd + (size_t)(ks * 128) * NE;  // wave-uniform pointer
    const float* bsqw = s_hbsq + ks * 128;
    float best  = 3.4e38f;
    int   bestk = ks * 128;
    for (int k = 0; k < 128; ++k) {
        float a0 = 0.f, a1 = 0.f, a2 = 0.f, a3 = 0.f;
#pragma unroll
        for (int e = 0; e < 64; e += 4) {
            a0 = fmaf(crow[e],     xr[e >> 2].x, a0);   // s_load + v_fma(v,s,v)
            a1 = fmaf(crow[e + 1], xr[e >> 2].y, a1);
            a2 = fmaf(crow[e + 2], xr[e >> 2].z, a2);
            a3 = fmaf(crow[e + 3], xr[e >> 2].w, a3);
        }
        crow += NE;
        float dist = bsqw[k] - ((a0 + a1) + (a2 + a3));
        if (dist < best) { best = dist; bestk = ks * 128 + k; }  // strict <: first idx wins
    }
    s_best[ks][bl] = best;
    s_idx[ks][bl]  = bestk;
    __syncthreads();

    // phase c: per-b reduce over the 8 ascending k-eighths (strict < keeps earliest)
    if (t < 128) {
        float bv = s_best[0][t];
        int   bk = s_idx[0][t];
#pragma unroll
        for (int j = 1; j < 8; ++j) {
            float ob = s_best[j][t];
            if (ob < bv) { bv = ob; bk = s_idx[j][t]; }
        }
        s_kf[t] = bk;
        atomicAdd(&s_cnt[bk], 1);    // LDS histogram
    }
    __syncthreads();

    // phase d: one-hot rows. Wave wv owns rows wv*8..wv*8+7; 4KB contiguous per row.
    for (int rr = 0; rr < 8; ++rr) {
        int r  = wv * 8 + rr;
        int kk = s_kf[r];
        float* orow = oh + (size_t)(bq * 128 + r) * (ND * NK) + d * NK;
#pragma unroll
        for (int j = 0; j < 4; ++j) {
            int k0 = j * 256 + lane * 4;
            float4 o;
            o.x = (k0     == kk) ? 1.f : 0.f;
            o.y = (k0 + 1 == kk) ? 1.f : 0.f;
            o.z = (k0 + 2 == kk) ? 1.f : 0.f;
            o.w = (k0 + 3 == kk) ? 1.f : 0.f;
            *(float4*)(orow + k0) = o;
        }
    }

    // phase e+f: cw rows (exact reference arithmetic x+(c-x)) + scatter into ncb
    for (int rr = 0; rr < 8; ++rr) {
        int r  = wv * 8 + rr;
        int kk = s_kf[r];
        int br = bq * 128 + r;
        float xv = x[(size_t)br * (ND * NE) + d * NE + lane];
        float cv = cbd[(size_t)kk * NE + lane];
        cw[(size_t)br * (ND * NE) + d * NE + lane] = xv + (cv - xv);
        float scale = GAINF / (ema[d * NK + kk] + EPSF);
        atomicAdd(&ncb[(size_t)d * (NK * NE) + (size_t)kk * NE + lane], scale * xv);
    }

    // phase g: flush histogram into nema (<= 4 blocks collide per bin)
    {
        int c = s_cnt[t];
        if (c) atomicAdd(&nema[d * NK + t], GAINF * (float)c);
    }
}

extern "C" void kernel_launch(void* const* d_in, const int* in_sizes, int n_in,
                              void* d_out, int out_size, void* d_ws, size_t ws_size,
                              hipStream_t stream) {
    const float* x   = (const float*)d_in[0];   // [512,4096]
    const float* cb  = (const float*)d_in[1];   // [64,1024,64]
    const float* ema = (const float*)d_in[2];   // [64,1024]
    (void)d_ws; (void)ws_size;

    float* out  = (float*)d_out;
    float* cw   = out;                          // 2,097,152
    float* oh   = out + 2097152;                // 33,554,432
    float* ncb  = out + 2097152 + 33554432;     // 4,194,304
    float* nema = ncb + 4194304;                // 65,536

    k_pre<<<4160, 256, 0, stream>>>(cb, ema, ncb, nema);

    dim3 g_fused(64, 4);                        // d on x -> XCD-aligned codebook reuse
    k_fused<<<g_fused, 1024, 0, stream>>>(x, cb, ema, cw, oh, ncb, nema);
}